// Round 6
// baseline (8819.012 us; speedup 1.0000x reference)
//
#include <hip/hip_runtime.h>
#include <hip/hip_bf16.h>
#include <stdint.h>

typedef unsigned short u16;
typedef uint32_t u32;
typedef unsigned long long u64;
typedef float f32x4 __attribute__((ext_vector_type(4)));
typedef __bf16 bf16x8 __attribute__((ext_vector_type(8)));

__device__ inline u16 f2bf(float f) {
  __bf16 h = (__bf16)f;                 // RTNE
  return __builtin_bit_cast(u16, h);
}
__device__ inline float bf2f(u16 u) {
  u32 x = ((u32)u) << 16;
  return __builtin_bit_cast(float, x);
}
__device__ inline f32x4 mfma16(bf16x8 a, bf16x8 b, f32x4 c) {
  return __builtin_amdgcn_mfma_f32_16x16x32_bf16(a, b, c, 0, 0, 0);
}
// split 8 contiguous fp32 into bf16 hi + lo fragments (cached loads)
__device__ inline void cvt8(const float* p, bf16x8& h, bf16x8& l) {
  f32x4 u = *(const f32x4*)p;
  f32x4 v = *(const f32x4*)(p + 4);
#pragma unroll
  for (int i = 0; i < 4; ++i) {
    float a = u[i]; __bf16 ah = (__bf16)a; h[i] = ah; l[i] = (__bf16)(a - (float)ah);
    float b = v[i]; __bf16 bh = (__bf16)b; h[i + 4] = bh; l[i + 4] = (__bf16)(b - (float)bh);
  }
}
// gather 8 k-strided fp32 (stride 1024 floats) into bf16 hi + lo fragments
__device__ inline void gather8(const float* p, bf16x8& h, bf16x8& l) {
#pragma unroll
  for (int e = 0; e < 8; ++e) {
    float f = p[(size_t)e * 1024];
    __bf16 x = (__bf16)f;
    h[e] = x; l[e] = (__bf16)(f - (float)x);
  }
}

// ---- coherence-point (bypass) state accessors: no fences needed anywhere ----
__device__ inline u64 ld64(const u64* p) {
  return __hip_atomic_load(p, __ATOMIC_RELAXED, __HIP_MEMORY_SCOPE_AGENT);
}
__device__ inline u32 ld32(const u32* p) {
  return __hip_atomic_load(p, __ATOMIC_RELAXED, __HIP_MEMORY_SCOPE_AGENT);
}
__device__ inline void st32(u32* p, u32 v) {
  __hip_atomic_store(p, v, __ATOMIC_RELAXED, __HIP_MEMORY_SCOPE_AGENT);
}
// word = hi_bf16 | lo_bf16<<16 ; split u64 (2 words) into hi-pair / lo-pair
struct U32Pair { u32 h, l; };
__device__ inline U32Pair unpack2(u64 w) {
  u32 a0 = (u32)w, a1 = (u32)(w >> 32);
  U32Pair r;
  r.h = __builtin_amdgcn_perm(a1, a0, 0x05040100);   // low16 of each word
  r.l = __builtin_amdgcn_perm(a1, a0, 0x07060302);   // high16 of each word
  return r;
}
__device__ inline void unpack_frag(u64 w0, u64 w1, u64 w2, u64 w3,
                                   bf16x8& fh, bf16x8& fl) {
  u32 H[4], L[4];
  U32Pair p0 = unpack2(w0); H[0] = p0.h; L[0] = p0.l;
  U32Pair p1 = unpack2(w1); H[1] = p1.h; L[1] = p1.l;
  U32Pair p2 = unpack2(w2); H[2] = p2.h; L[2] = p2.l;
  U32Pair p3 = unpack2(w3); H[3] = p3.h; L[3] = p3.l;
  struct W4 { u32 w[4]; };
  W4 hh = {{H[0], H[1], H[2], H[3]}};
  W4 ll = {{L[0], L[1], L[2], L[3]}};
  fh = __builtin_bit_cast(bf16x8, hh);
  fl = __builtin_bit_cast(bf16x8, ll);
}
// swizzled state layout: u32 index of element (b, j), plane = [32][1024]
// [q:j>>5]<<10 | [half:b>>4]<<9 | [epair:(j>>1)&3]<<7 | [kgroup:(j>>3)&3]<<5
// | [mrow:b&15]<<1 | [e0:j&1]   -> wave-instr bypass loads are 512B contiguous
__device__ inline u32 swz(int b, int j) {
  return ((u32)(j >> 5) << 10) | ((u32)(b >> 4) << 9) | ((u32)((j >> 1) & 3) << 7)
       | ((u32)((j >> 3) & 3) << 5) | ((u32)(b & 15) << 1) | (u32)(j & 1);
}

struct RecArgs {
  const float* x;
  const float *W_ix, *W_ih, *W_ic, *W_fx, *W_fh, *W_fc, *W_cx, *W_ch;
  const float *W_ox, *W_oh, *W_oc;
  const float *b_i, *b_f, *b_c, *b_o;
  u32 *hP, *cP;          // packed hi|lo state planes, swizzled, 128KB each
  u32* flags;            // 256 per-block epoch flags (1KB)
  float* out;
};

// All-to-all flag barrier: each block stores its own epoch flag (no RMW, no
// contention), wave 0 polls all 256 flags in parallel (4 words/lane) with a
// __ballot reduce. Monotonic epochs + ">=" compare. Iteration-capped.
__device__ inline void gbar(u32* flags, unsigned ep, int bid) {
  __syncthreads();                     // drains vmcnt: bypass stores at IF$
  if (threadIdx.x < 64) {
    if (threadIdx.x == 0) st32(flags + bid, ep);
    const int l4 = (int)threadIdx.x * 4;
    int it = 0;
    while (it < 300000) {
      u32 v0 = ld32(flags + l4 + 0);
      u32 v1 = ld32(flags + l4 + 1);
      u32 v2 = ld32(flags + l4 + 2);
      u32 v3 = ld32(flags + l4 + 3);
      bool ok = (v0 >= ep) & (v1 >= ep) & (v2 >= ep) & (v3 >= ep);
      if (__ballot(ok) == ~0ull) break;
      __builtin_amdgcn_s_sleep(2);
      ++it;
    }
  }
  __syncthreads();
}

// Persistent LSTM: 256 blocks x 512 threads (8 waves). Block owns 4 H-columns
// of each gate. Wave w owns K-slice [w*128, w*128+128). Weights in registers
// (hi/lo bf16 MFMA B-frags). State via coherence-point bypass ops -> no cache
// fences. 2 grid barriers per step (structural).
__global__ __launch_bounds__(512, 2) void lstm_rec(RecArgs a) {
  __shared__ float scr[8 * 2 * 16 * 16];   // [wave][mt][row][col]

  const int tid = threadIdx.x;
  const int wg = blockIdx.x;
  const int j0 = wg * 4;
  const int lane = tid & 63;
  const int wave = tid >> 6;
  const int mrow = lane & 15;               // A-row (batch) lane index
  const int kgroup = lane >> 4;             // k sub-block 0..3
  const int kq = kgroup * 8;
  const int kw = wave * 128;                // per-wave K slice
  const int col = lane & 15;                // B/D column lane index
  const int rq = (lane >> 4) * 4;           // D row quad base
  const int fbase = (kgroup << 4) | mrow;   // per-lane swizzle base (u64 idx)

  const u64* H64 = (const u64*)a.hP;
  const u64* C64 = (const u64*)a.cP;

  // ---- one-time: B-fragments (weights) -> registers, hi/lo split ----
  const int fjj = col >> 2, fg = col & 3;   // col = jj*4 + g
  const int fj = j0 + fjj;
  const float* Wx = (fg == 0) ? a.W_ix : (fg == 1) ? a.W_fx : (fg == 2) ? a.W_cx : a.W_ox;
  const float* Wh = (fg == 0) ? a.W_ih : (fg == 1) ? a.W_fh : (fg == 2) ? a.W_ch : a.W_oh;
  const float* Wc = (fg == 0) ? a.W_ic : (fg == 1) ? a.W_fc : (fg == 3) ? a.W_oc : a.W_ic;

  bf16x8 bxh[4], bxl[4], bhh[4], bhl[4], bch[4], bcl[4];
#pragma unroll
  for (int ks = 0; ks < 4; ++ks) {
    const size_t k8 = (size_t)(kw + ks * 32 + kq);
    gather8(Wx + k8 * 1024 + fj, bxh[ks], bxl[ks]);
    gather8(Wh + k8 * 1024 + fj, bhh[ks], bhl[ks]);
    if (fg != 2) {
      gather8(Wc + k8 * 1024 + fj, bch[ks], bcl[ks]);
    } else {
      bf16x8 z = {};
      bch[ks] = z; bcl[ks] = z;
    }
  }

  // elementwise thread constants (threads 0..127: b = tid>>2, jj = tid&3)
  const int eb = tid >> 2, ejj = tid & 3, ej = j0 + (tid & 3);
  const u32 sidx = swz(eb, ej);
  // ---- zero own slice of state (bypass stores) ----
  if (tid < 128) {
    st32(a.hP + sidx, 0u);
    st32(a.cP + sidx, 0u);
  }
  float bi = 0.f, bfv = 0.f, bcv = 0.f, bo = 0.f;
  if (tid < 128) {
    bi = a.b_i[ej]; bfv = a.b_f[eb * 1024 + ej]; bcv = a.b_c[ej]; bo = a.b_o[ej];
  }
  unsigned ep = 0;
  gbar(a.flags, ++ep, wg);

  float c_reg = 0.f, o_pre = 0.f;
  // carried c_{t-1} fragments (phase2(t-1) loads reused as phase1(t) peephole A)
  bf16x8 cfh0[4] = {}, cfl0[4] = {}, cfh1[4] = {}, cfl1[4] = {};

  for (int t = 0; t < 512; ++t) {
    // ======== phase 1: pre-gates = x@Wx + h@Wh (+ c_{t-1}@Wc peephole) ========
    f32x4 acc0 = {}, acc1 = {}, pc0 = {}, pc1 = {};
#pragma unroll
    for (int ks = 0; ks < 4; ++ks) {
      const int ka = kw + ks * 32 + kq;
      const int ib = (((wave << 2) + ks) << 9) | fbase;
      // h_{t-1} fragments: coalesced bypass loads + perm-unpack
      u64 h00 = ld64(H64 + ib),             h01v = ld64(H64 + ib + (1 << 6));
      u64 h02 = ld64(H64 + ib + (2 << 6)),  h03  = ld64(H64 + ib + (3 << 6));
      u64 h10 = ld64(H64 + ib + (1 << 8)),  h11  = ld64(H64 + ib + (1 << 8) + (1 << 6));
      u64 h12 = ld64(H64 + ib + (1 << 8) + (2 << 6));
      u64 h13 = ld64(H64 + ib + (1 << 8) + (3 << 6));
      bf16x8 ah0, al0, ah1, al1;
      unpack_frag(h00, h01v, h02, h03, ah0, al0);
      unpack_frag(h10, h11, h12, h13, ah1, al1);
      // x fragments (cached, L2-resident)
      bf16x8 xh0, xl0, xh1, xl1;
      const float* xp = a.x + ((size_t)(t * 32 + mrow) << 10) + ka;
      cvt8(xp, xh0, xl0);
      cvt8(xp + (16 << 10), xh1, xl1);
      // x term (3 cross), h term (3), c peephole from carried frags (3)
      acc0 = mfma16(xh0, bxh[ks], acc0);
      acc0 = mfma16(xl0, bxh[ks], acc0);
      acc0 = mfma16(xh0, bxl[ks], acc0);
      acc0 = mfma16(ah0, bhh[ks], acc0);
      acc0 = mfma16(al0, bhh[ks], acc0);
      acc0 = mfma16(ah0, bhl[ks], acc0);
      pc0  = mfma16(cfh0[ks], bch[ks], pc0);
      pc0  = mfma16(cfl0[ks], bch[ks], pc0);
      pc0  = mfma16(cfh0[ks], bcl[ks], pc0);
      acc1 = mfma16(xh1, bxh[ks], acc1);
      acc1 = mfma16(xl1, bxh[ks], acc1);
      acc1 = mfma16(xh1, bxl[ks], acc1);
      acc1 = mfma16(ah1, bhh[ks], acc1);
      acc1 = mfma16(al1, bhh[ks], acc1);
      acc1 = mfma16(ah1, bhl[ks], acc1);
      pc1  = mfma16(cfh1[ks], bch[ks], pc1);
      pc1  = mfma16(cfl1[ks], bch[ks], pc1);
      pc1  = mfma16(cfh1[ks], bcl[ks], pc1);
    }
    {
      const bool take_pc = (col & 3) != 3;   // o-gate peephole deferred to phase 2
#pragma unroll
      for (int v = 0; v < 4; ++v) {
        scr[((wave * 2 + 0) * 16 + rq + v) * 16 + col] = acc0[v] + (take_pc ? pc0[v] : 0.f);
        scr[((wave * 2 + 1) * 16 + rq + v) * 16 + col] = acc1[v] + (take_pc ? pc1[v] : 0.f);
      }
    }
    __syncthreads();
    if (tid < 128) {
      float pre[4];
#pragma unroll
      for (int g = 0; g < 4; ++g) {
        float s = 0.f;
#pragma unroll
        for (int w = 0; w < 8; ++w)
          s += scr[((w * 2 + (eb >> 4)) * 16 + (eb & 15)) * 16 + ejj * 4 + g];
        pre[g] = s;
      }
      float iv = 1.f / (1.f + expf(-(pre[0] + bi)));
      float fv = 1.f / (1.f + expf(-(pre[1] + bfv)));
      float cv = tanhf(pre[2] + bcv);
      c_reg = fv * c_reg + iv * cv;           // fp32 carry, owner thread
      u16 chi = f2bf(c_reg);
      u16 clo = f2bf(c_reg - bf2f(chi));
      st32(a.cP + sidx, (u32)chi | ((u32)clo << 16));
      o_pre = pre[3] + bo;
    }
    gbar(a.flags, ++ep, wg);                  // c_t visible device-wide

    // ======== phase 2: o-gate peephole = c_t @ W_oc ========
    f32x4 a20 = {}, a21 = {};
#pragma unroll
    for (int ks = 0; ks < 4; ++ks) {
      const int ib = (((wave << 2) + ks) << 9) | fbase;
      u64 c00 = ld64(C64 + ib),             c01v = ld64(C64 + ib + (1 << 6));
      u64 c02 = ld64(C64 + ib + (2 << 6)),  c03  = ld64(C64 + ib + (3 << 6));
      u64 c10 = ld64(C64 + ib + (1 << 8)),  c11  = ld64(C64 + ib + (1 << 8) + (1 << 6));
      u64 c12 = ld64(C64 + ib + (1 << 8) + (2 << 6));
      u64 c13 = ld64(C64 + ib + (1 << 8) + (3 << 6));
      unpack_frag(c00, c01v, c02, c03, cfh0[ks], cfl0[ks]);   // save as carry
      unpack_frag(c10, c11, c12, c13, cfh1[ks], cfl1[ks]);
      a20 = mfma16(cfh0[ks], bch[ks], a20);
      a20 = mfma16(cfl0[ks], bch[ks], a20);
      a20 = mfma16(cfh0[ks], bcl[ks], a20);
      a21 = mfma16(cfh1[ks], bch[ks], a21);
      a21 = mfma16(cfl1[ks], bch[ks], a21);
      a21 = mfma16(cfh1[ks], bcl[ks], a21);
    }
#pragma unroll
    for (int v = 0; v < 4; ++v) {
      scr[((wave * 2 + 0) * 16 + rq + v) * 16 + col] = a20[v];
      scr[((wave * 2 + 1) * 16 + rq + v) * 16 + col] = a21[v];
    }
    __syncthreads();
    if (tid < 128) {
      float s = o_pre;
#pragma unroll
      for (int w = 0; w < 8; ++w)
        s += scr[((w * 2 + (eb >> 4)) * 16 + (eb & 15)) * 16 + ejj * 4 + 3];
      float ov = 1.f / (1.f + expf(-s));
      float hv = ov * tanhf(c_reg);
      u16 hhi = f2bf(hv);
      u16 hlo = f2bf(hv - bf2f(hhi));
      st32(a.hP + sidx, (u32)hhi | ((u32)hlo << 16));
      if (t == 511) a.out[eb * 1024 + ej] = hv;
    }
    gbar(a.flags, ++ep, wg);                  // h_t visible device-wide
  }
}

extern "C" void kernel_launch(void* const* d_in, const int* in_sizes, int n_in,
                              void* d_out, int out_size, void* d_ws, size_t ws_size,
                              hipStream_t stream) {
  (void)in_sizes; (void)n_in; (void)out_size;
  RecArgs ra;
  ra.x    = (const float*)d_in[0];
  ra.W_ix = (const float*)d_in[1];
  ra.W_ih = (const float*)d_in[2];
  ra.W_ic = (const float*)d_in[3];
  ra.W_fx = (const float*)d_in[4];
  ra.W_fh = (const float*)d_in[5];
  ra.W_fc = (const float*)d_in[6];
  ra.W_cx = (const float*)d_in[7];
  ra.W_ch = (const float*)d_in[8];
  ra.W_ox = (const float*)d_in[9];
  ra.W_oh = (const float*)d_in[10];
  ra.W_oc = (const float*)d_in[11];
  ra.b_i  = (const float*)d_in[12];
  ra.b_f  = (const float*)d_in[13];
  ra.b_c  = (const float*)d_in[14];
  ra.b_o  = (const float*)d_in[15];

  char* ws = (char*)d_ws;
  size_t off = 0;
  auto alloc = [&](size_t bytes) {
    char* p = ws + off;
    off = (off + bytes + 255) & ~(size_t)255;
    return p;
  };
  ra.hP    = (u32*)alloc(32 * 1024 * 4);   // packed h (hi|lo), swizzled
  ra.cP    = (u32*)alloc(32 * 1024 * 4);   // packed c (hi|lo), swizzled
  ra.flags = (u32*)alloc(1024);            // 256 per-block epoch flags
  ra.out   = (float*)d_out;
  if (off > ws_size) return;               // visible failure if ws too small

  (void)hipMemsetAsync(ra.flags, 0, 1024, stream);  // reset flags each launch

  void* args[] = {&ra};
  hipError_t e = hipLaunchCooperativeKernel((void*)lstm_rec, dim3(256), dim3(512),
                                            args, 0, stream);
  if (e != hipSuccess) {
    // co-residency still holds: 1 block/CU x 256 blocks on 256 CUs
    lstm_rec<<<dim3(256), dim3(512), 0, stream>>>(ra);
  }
}

// Round 7
// 7428.140 us; speedup vs baseline: 1.1872x; 1.1872x over previous
//
#include <hip/hip_runtime.h>
#include <hip/hip_bf16.h>
#include <stdint.h>

typedef unsigned short u16;
typedef uint32_t u32;
typedef unsigned long long u64;
typedef float f32x4 __attribute__((ext_vector_type(4)));
typedef __bf16 bf16x8 __attribute__((ext_vector_type(8)));

__device__ inline u16 f2bf(float f) {
  __bf16 h = (__bf16)f;                 // RTNE
  return __builtin_bit_cast(u16, h);
}
__device__ inline float bf2f(u16 u) {
  u32 x = ((u32)u) << 16;
  return __builtin_bit_cast(float, x);
}
__device__ inline f32x4 mfma16(bf16x8 a, bf16x8 b, f32x4 c) {
  return __builtin_amdgcn_mfma_f32_16x16x32_bf16(a, b, c, 0, 0, 0);
}
// split 8 contiguous fp32 into bf16 hi + lo fragments (cached loads)
__device__ inline void cvt8(const float* p, bf16x8& h, bf16x8& l) {
  f32x4 u = *(const f32x4*)p;
  f32x4 v = *(const f32x4*)(p + 4);
#pragma unroll
  for (int i = 0; i < 4; ++i) {
    float a = u[i]; __bf16 ah = (__bf16)a; h[i] = ah; l[i] = (__bf16)(a - (float)ah);
    float b = v[i]; __bf16 bh = (__bf16)b; h[i + 4] = bh; l[i + 4] = (__bf16)(b - (float)bh);
  }
}
// gather 8 k-strided fp32 (stride 1024 floats) into bf16 hi + lo fragments
__device__ inline void gather8(const float* p, bf16x8& h, bf16x8& l) {
#pragma unroll
  for (int e = 0; e < 8; ++e) {
    float f = p[(size_t)e * 1024];
    __bf16 x = (__bf16)f;
    h[e] = x; l[e] = (__bf16)(f - (float)x);
  }
}

// ---- coherence-point (bypass) state accessors ----
__device__ inline u64 ld64(const u64* p) {
  return __hip_atomic_load(p, __ATOMIC_RELAXED, __HIP_MEMORY_SCOPE_AGENT);
}
__device__ inline void st32(u32* p, u32 v) {
  __hip_atomic_store(p, v, __ATOMIC_RELAXED, __HIP_MEMORY_SCOPE_AGENT);
}

// bf16 state plane [32 b][1024 j], 64KB, k-contiguous layout (u16 units):
//   idx16(b,j) = (j>>3)<<8 | ((j>>2)&1)<<7 | (b&31)<<2 | (j&3)
// A wave's fragment (8 k-elems, one row) = 2 coalesced ld64:
//   u64 idx = (j8<<6)+row  and  (j8<<6)+32+row     (j8 = k/8)
struct B16Pair { u64 a, b; };
__device__ inline bf16x8 ldfrag(const u64* base, int j8, int row) {
  B16Pair p;
  p.a = ld64(base + (j8 << 6) + row);
  p.b = ld64(base + (j8 << 6) + 32 + row);
  return __builtin_bit_cast(bf16x8, p);
}

struct RecArgs {
  const float* x;
  const float *W_ix, *W_ih, *W_ic, *W_fx, *W_fh, *W_fc, *W_cx, *W_ch;
  const float *W_ox, *W_oh, *W_oc;
  const float *b_i, *b_f, *b_c, *b_o;
  u32 *hB, *cB;          // bf16 state planes (u32-pair granularity), 64KB each
  unsigned* cnt;
  float* out;
};

// Round-5 single-counter barrier (measured best): relaxed RMW + relaxed poll.
__device__ inline void gbar(unsigned* cnt, unsigned target) {
  __syncthreads();                     // drains vmcnt: bypass stores at IF$
  if (threadIdx.x == 0) {
    __hip_atomic_fetch_add(cnt, 1u, __ATOMIC_RELAXED, __HIP_MEMORY_SCOPE_AGENT);
    int it = 0;
    while (__hip_atomic_load(cnt, __ATOMIC_RELAXED, __HIP_MEMORY_SCOPE_AGENT) < target
           && it < 400000) {
      __builtin_amdgcn_s_sleep(2);
      ++it;
    }
  }
  __syncthreads();
}

// Persistent LSTM: 256 blocks x 512 threads (8 waves). Block owns 4 H-columns
// of each gate. Wave w owns K-slice [w*128, w*128+128). Weights register-
// resident (hi/lo bf16). State = plain bf16 (halved L3 broadcast: 32MB/step).
__global__ __launch_bounds__(512, 2) void lstm_rec(RecArgs a) {
  __shared__ float scr[8 * 2 * 16 * 16];   // [wave][mt][row][col]

  const int tid = threadIdx.x;
  const int wg = blockIdx.x;
  const int j0 = wg * 4;
  const int lane = tid & 63;
  const int wave = tid >> 6;
  const int mrow = lane & 15;               // A-row (batch) lane index
  const int kgroup = lane >> 4;             // k sub-block 0..3
  const int kq = kgroup * 8;
  const int kw = wave * 128;                // per-wave K slice
  const int col = lane & 15;                // B/D column lane index
  const int rq = (lane >> 4) * 4;           // D row quad base

  const u64* H64 = (const u64*)a.hB;
  const u64* C64 = (const u64*)a.cB;

  // ---- one-time: B-fragments (weights) -> registers, hi/lo split ----
  const int fjj = col >> 2, fg = col & 3;   // col = jj*4 + g
  const int fj = j0 + fjj;
  const float* Wx = (fg == 0) ? a.W_ix : (fg == 1) ? a.W_fx : (fg == 2) ? a.W_cx : a.W_ox;
  const float* Wh = (fg == 0) ? a.W_ih : (fg == 1) ? a.W_fh : (fg == 2) ? a.W_ch : a.W_oh;
  const float* Wc = (fg == 0) ? a.W_ic : (fg == 1) ? a.W_fc : (fg == 3) ? a.W_oc : a.W_ic;

  bf16x8 bxh[4], bxl[4], bhh[4], bhl[4], bch[4], bcl[4];
#pragma unroll
  for (int ks = 0; ks < 4; ++ks) {
    const size_t k8 = (size_t)(kw + ks * 32 + kq);
    gather8(Wx + k8 * 1024 + fj, bxh[ks], bxl[ks]);
    gather8(Wh + k8 * 1024 + fj, bhh[ks], bhl[ks]);
    if (fg != 2) {
      gather8(Wc + k8 * 1024 + fj, bch[ks], bcl[ks]);
    } else {
      bf16x8 z = {};
      bch[ks] = z; bcl[ks] = z;
    }
  }

  // elementwise thread constants (threads 0..127: b = tid>>2, jj = tid&3)
  const int eb = tid >> 2, ejj = tid & 3, ej = j0 + (tid & 3);
  // u32 index of the (j even, j odd) pair this thread's element lives in
  const u32 swidx = ((u32)(ej >> 3) << 7) | ((u32)((ej >> 2) & 1) << 6)
                  | ((u32)eb << 1) | ((u32)(ej >> 1) & 1);
  // ---- zero own slice of state (bypass stores, even threads store pairs) ----
  if (tid < 128 && (tid & 1) == 0) {
    st32(a.hB + swidx, 0u);
    st32(a.cB + swidx, 0u);
  }
  float bi = 0.f, bfv = 0.f, bcv = 0.f, bo = 0.f;
  if (tid < 128) {
    bi = a.b_i[ej]; bfv = a.b_f[eb * 1024 + ej]; bcv = a.b_c[ej]; bo = a.b_o[ej];
  }
  unsigned ep = 0;
  gbar(a.cnt, (++ep) * gridDim.x);

  float c_reg = 0.f, o_pre = 0.f;
  // carried c_{t-1} fragments (phase2(t-1) loads reused as phase1(t) peephole A)
  bf16x8 cf0[4] = {}, cf1[4] = {};

  for (int t = 0; t < 512; ++t) {
    // ======== phase 1: pre-gates = x@Wx + h@Wh (+ c_{t-1}@Wc peephole) ========
    f32x4 acc0 = {}, acc1 = {}, pc0 = {}, pc1 = {};
#pragma unroll
    for (int ks = 0; ks < 4; ++ks) {
      const int ka = kw + ks * 32 + kq;
      const int j8 = wave * 16 + ks * 4 + kgroup;
      // h_{t-1} fragments: 2 coalesced bypass ld64 each, no unpack
      bf16x8 ah0 = ldfrag(H64, j8, mrow);
      bf16x8 ah1 = ldfrag(H64, j8, mrow + 16);
      // x fragments (cached, L2-resident), full hi/lo split
      bf16x8 xh0, xl0, xh1, xl1;
      const float* xp = a.x + ((size_t)(t * 32 + mrow) << 10) + ka;
      cvt8(xp, xh0, xl0);
      cvt8(xp + (16 << 10), xh1, xl1);
      // x: 3 cross terms; h: 2 terms (hi@Whi + hi@Wlo); c peephole: 2 terms
      acc0 = mfma16(xh0, bxh[ks], acc0);
      acc0 = mfma16(xl0, bxh[ks], acc0);
      acc0 = mfma16(xh0, bxl[ks], acc0);
      acc0 = mfma16(ah0, bhh[ks], acc0);
      acc0 = mfma16(ah0, bhl[ks], acc0);
      pc0  = mfma16(cf0[ks], bch[ks], pc0);
      pc0  = mfma16(cf0[ks], bcl[ks], pc0);
      acc1 = mfma16(xh1, bxh[ks], acc1);
      acc1 = mfma16(xl1, bxh[ks], acc1);
      acc1 = mfma16(xh1, bxl[ks], acc1);
      acc1 = mfma16(ah1, bhh[ks], acc1);
      acc1 = mfma16(ah1, bhl[ks], acc1);
      pc1  = mfma16(cf1[ks], bch[ks], pc1);
      pc1  = mfma16(cf1[ks], bcl[ks], pc1);
    }
    {
      const bool take_pc = (col & 3) != 3;   // o-gate peephole deferred to phase 2
#pragma unroll
      for (int v = 0; v < 4; ++v) {
        scr[((wave * 2 + 0) * 16 + rq + v) * 16 + col] = acc0[v] + (take_pc ? pc0[v] : 0.f);
        scr[((wave * 2 + 1) * 16 + rq + v) * 16 + col] = acc1[v] + (take_pc ? pc1[v] : 0.f);
      }
    }
    __syncthreads();
    if (tid < 128) {
      float pre[4];
#pragma unroll
      for (int g = 0; g < 4; ++g) {
        float s = 0.f;
#pragma unroll
        for (int w = 0; w < 8; ++w)
          s += scr[((w * 2 + (eb >> 4)) * 16 + (eb & 15)) * 16 + ejj * 4 + g];
        pre[g] = s;
      }
      float iv = 1.f / (1.f + expf(-(pre[0] + bi)));
      float fv = 1.f / (1.f + expf(-(pre[1] + bfv)));
      float cv = tanhf(pre[2] + bcv);
      c_reg = fv * c_reg + iv * cv;           // fp32 carry, owner thread
      u32 cb = (u32)f2bf(c_reg);
      u32 cpart = __shfl_xor(cb, 1);
      if ((tid & 1) == 0) st32(a.cB + swidx, cb | (cpart << 16));
      o_pre = pre[3] + bo;
    }
    gbar(a.cnt, (++ep) * gridDim.x);          // c_t visible device-wide

    // ======== phase 2: o-gate peephole = c_t @ W_oc ========
    f32x4 a20 = {}, a21 = {};
#pragma unroll
    for (int ks = 0; ks < 4; ++ks) {
      const int j8 = wave * 16 + ks * 4 + kgroup;
      cf0[ks] = ldfrag(C64, j8, mrow);        // save as carry for phase1(t+1)
      cf1[ks] = ldfrag(C64, j8, mrow + 16);
      a20 = mfma16(cf0[ks], bch[ks], a20);
      a20 = mfma16(cf0[ks], bcl[ks], a20);
      a21 = mfma16(cf1[ks], bch[ks], a21);
      a21 = mfma16(cf1[ks], bcl[ks], a21);
    }
#pragma unroll
    for (int v = 0; v < 4; ++v) {
      scr[((wave * 2 + 0) * 16 + rq + v) * 16 + col] = a20[v];
      scr[((wave * 2 + 1) * 16 + rq + v) * 16 + col] = a21[v];
    }
    __syncthreads();
    if (tid < 128) {
      float s = o_pre;
#pragma unroll
      for (int w = 0; w < 8; ++w)
        s += scr[((w * 2 + (eb >> 4)) * 16 + (eb & 15)) * 16 + ejj * 4 + 3];
      float ov = 1.f / (1.f + expf(-s));
      float hv = ov * tanhf(c_reg);
      u32 hb = (u32)f2bf(hv);
      u32 hpart = __shfl_xor(hb, 1);
      if ((tid & 1) == 0) st32(a.hB + swidx, hb | (hpart << 16));
      if (t == 511) a.out[eb * 1024 + ej] = hv;
    }
    gbar(a.cnt, (++ep) * gridDim.x);          // h_t visible device-wide
  }
}

extern "C" void kernel_launch(void* const* d_in, const int* in_sizes, int n_in,
                              void* d_out, int out_size, void* d_ws, size_t ws_size,
                              hipStream_t stream) {
  (void)in_sizes; (void)n_in; (void)out_size;
  RecArgs ra;
  ra.x    = (const float*)d_in[0];
  ra.W_ix = (const float*)d_in[1];
  ra.W_ih = (const float*)d_in[2];
  ra.W_ic = (const float*)d_in[3];
  ra.W_fx = (const float*)d_in[4];
  ra.W_fh = (const float*)d_in[5];
  ra.W_fc = (const float*)d_in[6];
  ra.W_cx = (const float*)d_in[7];
  ra.W_ch = (const float*)d_in[8];
  ra.W_ox = (const float*)d_in[9];
  ra.W_oh = (const float*)d_in[10];
  ra.W_oc = (const float*)d_in[11];
  ra.b_i  = (const float*)d_in[12];
  ra.b_f  = (const float*)d_in[13];
  ra.b_c  = (const float*)d_in[14];
  ra.b_o  = (const float*)d_in[15];

  char* ws = (char*)d_ws;
  size_t off = 0;
  auto alloc = [&](size_t bytes) {
    char* p = ws + off;
    off = (off + bytes + 255) & ~(size_t)255;
    return p;
  };
  ra.hB  = (u32*)alloc(32 * 1024 * 2);   // bf16 h plane, k-contiguous layout
  ra.cB  = (u32*)alloc(32 * 1024 * 2);   // bf16 c plane
  ra.cnt = (unsigned*)alloc(256);
  ra.out = (float*)d_out;
  if (off > ws_size) return;             // visible failure if ws too small

  (void)hipMemsetAsync(ra.cnt, 0, 4, stream);  // reset barrier counter

  void* args[] = {&ra};
  hipError_t e = hipLaunchCooperativeKernel((void*)lstm_rec, dim3(256), dim3(512),
                                            args, 0, stream);
  if (e != hipSuccess) {
    // co-residency still holds: 1 block/CU x 256 blocks on 256 CUs
    lstm_rec<<<dim3(256), dim3(512), 0, stream>>>(ra);
  }
}

// Round 8
// 5121.712 us; speedup vs baseline: 1.7219x; 1.4503x over previous
//
#include <hip/hip_runtime.h>
#include <hip/hip_bf16.h>
#include <stdint.h>

typedef unsigned short u16;
typedef uint32_t u32;
typedef unsigned long long u64;
typedef float f32x4 __attribute__((ext_vector_type(4)));
typedef __bf16 bf16x8 __attribute__((ext_vector_type(8)));

__device__ inline u16 f2bf(float f) {
  __bf16 h = (__bf16)f;                 // RTNE
  return __builtin_bit_cast(u16, h);
}
__device__ inline float bf2f(u16 u) {
  u32 x = ((u32)u) << 16;
  return __builtin_bit_cast(float, x);
}
__device__ inline f32x4 mfma16(bf16x8 a, bf16x8 b, f32x4 c) {
  return __builtin_amdgcn_mfma_f32_16x16x32_bf16(a, b, c, 0, 0, 0);
}
// split 8 contiguous fp32 into bf16 hi + lo fragments (cached loads)
__device__ inline void cvt8(const float* p, bf16x8& h, bf16x8& l) {
  f32x4 u = *(const f32x4*)p;
  f32x4 v = *(const f32x4*)(p + 4);
#pragma unroll
  for (int i = 0; i < 4; ++i) {
    float a = u[i]; __bf16 ah = (__bf16)a; h[i] = ah; l[i] = (__bf16)(a - (float)ah);
    float b = v[i]; __bf16 bh = (__bf16)b; h[i + 4] = bh; l[i + 4] = (__bf16)(b - (float)bh);
  }
}
// gather 8 k-strided fp32 (stride 1024 floats) into bf16 hi + lo fragments
__device__ inline void gather8(const float* p, bf16x8& h, bf16x8& l) {
#pragma unroll
  for (int e = 0; e < 8; ++e) {
    float f = p[(size_t)e * 1024];
    __bf16 x = (__bf16)f;
    h[e] = x; l[e] = (__bf16)(f - (float)x);
  }
}

// ---- coherence-point (bypass) accessors ----
__device__ inline u64 ld64(const u64* p) {
  return __hip_atomic_load(p, __ATOMIC_RELAXED, __HIP_MEMORY_SCOPE_AGENT);
}
__device__ inline u32 ld32(const u32* p) {
  return __hip_atomic_load(p, __ATOMIC_RELAXED, __HIP_MEMORY_SCOPE_AGENT);
}
__device__ inline void st32(u32* p, u32 v) {
  __hip_atomic_store(p, v, __ATOMIC_RELAXED, __HIP_MEMORY_SCOPE_AGENT);
}

// bf16 state plane [32 b][1024 j], 64KB, k-contiguous layout (u16 units):
//   idx16(b,j) = (j>>3)<<8 | ((j>>2)&1)<<7 | (b&31)<<2 | (j&3)
// A wave's fragment (8 k-elems, one row) = 2 coalesced ld64.
struct B16Pair { u64 a, b; };
__device__ inline bf16x8 ldfrag(const u64* base, int j8, int row) {
  B16Pair p;
  p.a = ld64(base + (j8 << 6) + row);
  p.b = ld64(base + (j8 << 6) + 32 + row);
  return __builtin_bit_cast(bf16x8, p);
}

struct RecArgs {
  const float* x;
  const float *W_ix, *W_ih, *W_ic, *W_fx, *W_fh, *W_fc, *W_cx, *W_ch;
  const float *W_ox, *W_oh, *W_oc;
  const float *b_i, *b_f, *b_c, *b_o;
  u32 *hB, *cB;          // bf16 state planes, 64KB each
  u32* flags;            // 256 packed per-block epoch flags (1KB)
  u32* done;             // root broadcast epoch (own line)
  float* out;
};

// 2-level tree barrier:
//  arrive:   thread0 stores flags[wg]=ep           (spread stores, no RMW)
//  detect:   block 0 waves 0-3 poll 64 flags each  (coalesced, 16 lines/iter)
//  publish:  block 0 thread0 stores done=ep        (dedicated read-only line)
//  release:  every block's thread0 polls done      (1 scalar dword/iter)
__device__ inline void gbar(u32* flags, u32* done, unsigned ep, int wg) {
  __syncthreads();                       // drains vmcnt: bypass stores at IF$
  const int tid = threadIdx.x;
  if (tid == 0) st32(flags + wg, ep);
  if (wg == 0) {
    const int wv = tid >> 6, ln = tid & 63;
    if (wv < 4) {
      int it = 0;
      for (;;) {
        u32 v = ld32(flags + wv * 64 + ln);
        if (__ballot(v >= ep) == ~0ull) break;
        if (++it > 400000) break;
        __builtin_amdgcn_s_sleep(1);
      }
    }
    __syncthreads();                     // all 4 quarter-groups confirmed
    if (tid == 0) st32(done, ep);
  }
  if (tid == 0) {
    int it = 0;
    while (ld32(done) < ep && it < 400000) {
      __builtin_amdgcn_s_sleep(1);
      ++it;
    }
  }
  __syncthreads();
}

// Persistent LSTM: 256 blocks x 512 threads (8 waves). Block owns 4 H-columns
// of each gate. Wave w owns K-slice [w*128, w*128+128). Weights register-
// resident (hi/lo bf16). State = plain bf16 via IF$-bypass (32MB/step bcast).
__global__ __launch_bounds__(512, 2) void lstm_rec(RecArgs a) {
  __shared__ float scr[8 * 2 * 16 * 16];   // [wave][mt][row][col]

  const int tid = threadIdx.x;
  const int wg = blockIdx.x;
  const int j0 = wg * 4;
  const int lane = tid & 63;
  const int wave = tid >> 6;
  const int mrow = lane & 15;               // A-row (batch) lane index
  const int kgroup = lane >> 4;             // k sub-block 0..3
  const int kq = kgroup * 8;
  const int kw = wave * 128;                // per-wave K slice
  const int col = lane & 15;                // B/D column lane index
  const int rq = (lane >> 4) * 4;           // D row quad base

  const u64* H64 = (const u64*)a.hB;
  const u64* C64 = (const u64*)a.cB;

  // ---- one-time: B-fragments (weights) -> registers, hi/lo split ----
  const int fjj = col >> 2, fg = col & 3;   // col = jj*4 + g
  const int fj = j0 + fjj;
  const float* Wx = (fg == 0) ? a.W_ix : (fg == 1) ? a.W_fx : (fg == 2) ? a.W_cx : a.W_ox;
  const float* Wh = (fg == 0) ? a.W_ih : (fg == 1) ? a.W_fh : (fg == 2) ? a.W_ch : a.W_oh;
  const float* Wc = (fg == 0) ? a.W_ic : (fg == 1) ? a.W_fc : (fg == 3) ? a.W_oc : a.W_ic;

  bf16x8 bxh[4], bxl[4], bhh[4], bhl[4], bch[4], bcl[4];
#pragma unroll
  for (int ks = 0; ks < 4; ++ks) {
    const size_t k8 = (size_t)(kw + ks * 32 + kq);
    gather8(Wx + k8 * 1024 + fj, bxh[ks], bxl[ks]);
    gather8(Wh + k8 * 1024 + fj, bhh[ks], bhl[ks]);
    if (fg != 2) {
      gather8(Wc + k8 * 1024 + fj, bch[ks], bcl[ks]);
    } else {
      bf16x8 z = {};
      bch[ks] = z; bcl[ks] = z;
    }
  }

  // elementwise thread constants (threads 0..127: b = tid>>2, jj = tid&3)
  const int eb = tid >> 2, ejj = tid & 3, ej = j0 + (tid & 3);
  // u32 index of the (j even, j odd) pair this thread's element lives in
  const u32 swidx = ((u32)(ej >> 3) << 7) | ((u32)((ej >> 2) & 1) << 6)
                  | ((u32)eb << 1) | ((u32)(ej >> 1) & 1);
  // ---- zero own slice of state (bypass stores, even threads store pairs) ----
  if (tid < 128 && (tid & 1) == 0) {
    st32(a.hB + swidx, 0u);
    st32(a.cB + swidx, 0u);
  }
  float bi = 0.f, bfv = 0.f, bcv = 0.f, bo = 0.f;
  if (tid < 128) {
    bi = a.b_i[ej]; bfv = a.b_f[eb * 1024 + ej]; bcv = a.b_c[ej]; bo = a.b_o[ej];
  }
  unsigned ep = 0;
  gbar(a.flags, a.done, ++ep, wg);

  float c_reg = 0.f, o_pre = 0.f;
  // carried c_{t-1} fragments (phase2(t-1) loads reused as phase1(t) peephole A)
  bf16x8 cf0[4] = {}, cf1[4] = {};

  for (int t = 0; t < 512; ++t) {
    // ======== phase 1: pre-gates = x@Wx + h@Wh (+ c_{t-1}@Wc peephole) ========
    f32x4 acc0 = {}, acc1 = {}, pc0 = {}, pc1 = {};
#pragma unroll
    for (int ks = 0; ks < 4; ++ks) {
      const int ka = kw + ks * 32 + kq;
      const int j8 = wave * 16 + ks * 4 + kgroup;
      // h_{t-1} fragments: 2 coalesced bypass ld64 each
      bf16x8 ah0 = ldfrag(H64, j8, mrow);
      bf16x8 ah1 = ldfrag(H64, j8, mrow + 16);
      // x fragments (cached, L2-resident), full hi/lo split
      bf16x8 xh0, xl0, xh1, xl1;
      const float* xp = a.x + ((size_t)(t * 32 + mrow) << 10) + ka;
      cvt8(xp, xh0, xl0);
      cvt8(xp + (16 << 10), xh1, xl1);
      // x: 3 cross terms; h: 2 terms; c peephole: 2 terms
      acc0 = mfma16(xh0, bxh[ks], acc0);
      acc0 = mfma16(xl0, bxh[ks], acc0);
      acc0 = mfma16(xh0, bxl[ks], acc0);
      acc0 = mfma16(ah0, bhh[ks], acc0);
      acc0 = mfma16(ah0, bhl[ks], acc0);
      pc0  = mfma16(cf0[ks], bch[ks], pc0);
      pc0  = mfma16(cf0[ks], bcl[ks], pc0);
      acc1 = mfma16(xh1, bxh[ks], acc1);
      acc1 = mfma16(xl1, bxh[ks], acc1);
      acc1 = mfma16(xh1, bxl[ks], acc1);
      acc1 = mfma16(ah1, bhh[ks], acc1);
      acc1 = mfma16(ah1, bhl[ks], acc1);
      pc1  = mfma16(cf1[ks], bch[ks], pc1);
      pc1  = mfma16(cf1[ks], bcl[ks], pc1);
    }
    {
      const bool take_pc = (col & 3) != 3;   // o-gate peephole deferred to phase 2
#pragma unroll
      for (int v = 0; v < 4; ++v) {
        scr[((wave * 2 + 0) * 16 + rq + v) * 16 + col] = acc0[v] + (take_pc ? pc0[v] : 0.f);
        scr[((wave * 2 + 1) * 16 + rq + v) * 16 + col] = acc1[v] + (take_pc ? pc1[v] : 0.f);
      }
    }
    __syncthreads();
    if (tid < 128) {
      float pre[4];
#pragma unroll
      for (int g = 0; g < 4; ++g) {
        float s = 0.f;
#pragma unroll
        for (int w = 0; w < 8; ++w)
          s += scr[((w * 2 + (eb >> 4)) * 16 + (eb & 15)) * 16 + ejj * 4 + g];
        pre[g] = s;
      }
      float iv = 1.f / (1.f + expf(-(pre[0] + bi)));
      float fv = 1.f / (1.f + expf(-(pre[1] + bfv)));
      float cv = tanhf(pre[2] + bcv);
      c_reg = fv * c_reg + iv * cv;           // fp32 carry, owner thread
      u32 cb = (u32)f2bf(c_reg);
      u32 cpart = __shfl_xor(cb, 1);
      if ((tid & 1) == 0) st32(a.cB + swidx, cb | (cpart << 16));
      o_pre = pre[3] + bo;
    }
    gbar(a.flags, a.done, ++ep, wg);          // c_t visible device-wide

    // ======== phase 2: o-gate peephole = c_t @ W_oc ========
    f32x4 a20 = {}, a21 = {};
#pragma unroll
    for (int ks = 0; ks < 4; ++ks) {
      const int j8 = wave * 16 + ks * 4 + kgroup;
      cf0[ks] = ldfrag(C64, j8, mrow);        // save as carry for phase1(t+1)
      cf1[ks] = ldfrag(C64, j8, mrow + 16);
      a20 = mfma16(cf0[ks], bch[ks], a20);
      a20 = mfma16(cf0[ks], bcl[ks], a20);
      a21 = mfma16(cf1[ks], bch[ks], a21);
      a21 = mfma16(cf1[ks], bcl[ks], a21);
    }
#pragma unroll
    for (int v = 0; v < 4; ++v) {
      scr[((wave * 2 + 0) * 16 + rq + v) * 16 + col] = a20[v];
      scr[((wave * 2 + 1) * 16 + rq + v) * 16 + col] = a21[v];
    }
    __syncthreads();
    if (tid < 128) {
      float s = o_pre;
#pragma unroll
      for (int w = 0; w < 8; ++w)
        s += scr[((w * 2 + (eb >> 4)) * 16 + (eb & 15)) * 16 + ejj * 4 + 3];
      float ov = 1.f / (1.f + expf(-s));
      float hv = ov * tanhf(c_reg);
      u32 hb = (u32)f2bf(hv);
      u32 hpart = __shfl_xor(hb, 1);
      if ((tid & 1) == 0) st32(a.hB + swidx, hb | (hpart << 16));
      if (t == 511) a.out[eb * 1024 + ej] = hv;
    }
    gbar(a.flags, a.done, ++ep, wg);          // h_t visible device-wide
  }
}

extern "C" void kernel_launch(void* const* d_in, const int* in_sizes, int n_in,
                              void* d_out, int out_size, void* d_ws, size_t ws_size,
                              hipStream_t stream) {
  (void)in_sizes; (void)n_in; (void)out_size;
  RecArgs ra;
  ra.x    = (const float*)d_in[0];
  ra.W_ix = (const float*)d_in[1];
  ra.W_ih = (const float*)d_in[2];
  ra.W_ic = (const float*)d_in[3];
  ra.W_fx = (const float*)d_in[4];
  ra.W_fh = (const float*)d_in[5];
  ra.W_fc = (const float*)d_in[6];
  ra.W_cx = (const float*)d_in[7];
  ra.W_ch = (const float*)d_in[8];
  ra.W_ox = (const float*)d_in[9];
  ra.W_oh = (const float*)d_in[10];
  ra.W_oc = (const float*)d_in[11];
  ra.b_i  = (const float*)d_in[12];
  ra.b_f  = (const float*)d_in[13];
  ra.b_c  = (const float*)d_in[14];
  ra.b_o  = (const float*)d_in[15];

  char* ws = (char*)d_ws;
  size_t off = 0;
  auto alloc = [&](size_t bytes) {
    char* p = ws + off;
    off = (off + bytes + 255) & ~(size_t)255;
    return p;
  };
  ra.hB    = (u32*)alloc(32 * 1024 * 2);   // bf16 h plane, k-contiguous layout
  ra.cB    = (u32*)alloc(32 * 1024 * 2);   // bf16 c plane
  ra.flags = (u32*)alloc(1024);            // 256 packed per-block epoch flags
  ra.done  = (u32*)alloc(256);             // root broadcast epoch (own line)
  ra.out   = (float*)d_out;
  if (off > ws_size) return;               // visible failure if ws too small

  (void)hipMemsetAsync(ra.flags, 0, 1024, stream);
  (void)hipMemsetAsync(ra.done, 0, 256, stream);

  void* args[] = {&ra};
  hipError_t e = hipLaunchCooperativeKernel((void*)lstm_rec, dim3(256), dim3(512),
                                            args, 0, stream);
  if (e != hipSuccess) {
    // co-residency still holds: 1 block/CU x 256 blocks on 256 CUs
    lstm_rec<<<dim3(256), dim3(512), 0, stream>>>(ra);
  }
}